// Round 9
// baseline (755.541 us; speedup 1.0000x reference)
//
#include <hip/hip_runtime.h>
#include <hip/hip_cooperative_groups.h>

namespace cg = cooperative_groups;

#define EMB 128
#define NBUC 1024          // coarse buckets: dst >> 7 (128 nodes per bucket)
#define PWB 64             // weight-prep blocks (64 x 512 = 32768 = both W)

typedef __attribute__((ext_vector_type(8))) short short8;   // 8 bf16 (4 VGPRs)
typedef __attribute__((ext_vector_type(4))) float f32x4;    // MFMA acc

// ---------------- bf16 helpers ----------------
__device__ __forceinline__ unsigned short f2bf(float f) {
    union { float f; unsigned int i; } v; v.f = f;
    unsigned int x = v.i;
    x += 0x7fffu + ((x >> 16) & 1u);   // round-to-nearest-even
    return (unsigned short)(x >> 16);
}
// a += d * unpack_bf16x4(v)
__device__ __forceinline__ void acc_fma4(uint2 v, float d,
                                         float& a0, float& a1, float& a2, float& a3) {
    union { unsigned int i; float f; } t;
    t.i = v.x << 16;          a0 = fmaf(d, t.f, a0);
    t.i = v.x & 0xffff0000u;  a1 = fmaf(d, t.f, a1);
    t.i = v.y << 16;          a2 = fmaf(d, t.f, a2);
    t.i = v.y & 0xffff0000u;  a3 = fmaf(d, t.f, a3);
}
// a += unpack_bf16x4(v)
__device__ __forceinline__ void acc_bf4(uint2 v,
                                        float& a0, float& a1, float& a2, float& a3) {
    union { unsigned int i; float f; } t;
    t.i = v.x << 16;          a0 += t.f;
    t.i = v.x & 0xffff0000u;  a1 += t.f;
    t.i = v.y << 16;          a2 += t.f;
    t.i = v.y & 0xffff0000u;  a3 += t.f;
}

// =====================================================================
// ONE cooperative kernel for the entire 2-layer GCN.
// Phases (separated by grid.sync()):
//   A0: zero bucket totals
//   A : edge histogram (blocks >= PWB) || W1/W2 pre-swizzle (blocks < PWB)
//   B : block 0 scans bucket totals -> base[], gcnt[]
//   C : reservation scatter (blocks < nb/2) || layer-1 GEMM (blocks >= nb/2)
//   D : bucket -> CSR (R, adj, dis)
//   E : fused gather1(dis-fold) + relu + bias + layer-2 GEMM (dis-scaled out)
//   F : gather2 (plain adds) + bias -> f32 out
// Gathers use the proven 32 thr/node + uint2 shape (fastest measured; the
// gather is random-granule-HBM-bound so shape changes only lose).
// LDS: one 17408-B arena reused per phase (max: gemm1 epilogue 64x136 bf16).
// __launch_bounds__(512,8): 8 waves/EU -> 32 waves/CU -> VGPR<=64 -> 4
// co-resident 512-thr blocks/CU, which the host grid sizing relies on.
// =====================================================================
__global__ __launch_bounds__(512, 8) void k_all(
    const int* __restrict__ src, const int* __restrict__ dst, int E,
    const float* __restrict__ emb,
    const float* __restrict__ W1, const float* __restrict__ b1,
    const float* __restrict__ W2, const float* __restrict__ b2,
    float* __restrict__ out, int N,
    int* __restrict__ tot, int* __restrict__ base, int* __restrict__ gcnt,
    int* __restrict__ R, int* __restrict__ adj, float* __restrict__ dis,
    unsigned short* __restrict__ W1s, unsigned short* __restrict__ W2s,
    int* __restrict__ part,
    unsigned short* __restrict__ Y1, unsigned short* __restrict__ Y2)
{
    cg::grid_group g = cg::this_grid();
    __shared__ __align__(16) char smem[17408];
    const int tid = threadIdx.x;
    const int bid = blockIdx.x;
    const int nb  = gridDim.x;
    const int wave = tid >> 6;
    const int lane = tid & 63;
    const int q = lane >> 4, nn = lane & 15;

    // ---------------- A0: zero bucket totals ----------------
    {
        int i = bid * 512 + tid;
        if (i < NBUC) tot[i] = 0;
    }
    g.sync();

    // ---------------- A: hist || weight pre-swizzle ----------------
    if (bid < PWB) {
        // Wb[kk][ct][q][nn][j] = W[kk*32+q*8+j][ct*16+nn]
        int gid = bid * 512 + tid;                 // 0..32767
        const float* W = (gid < 16384) ? W1 : W2;
        unsigned short* Ws = (gid < 16384) ? W1s : W2s;
        int idx = gid & 16383;
        int k = idx >> 7, n = idx & 127;
        int kk = k >> 5, qq = (k >> 3) & 3, j = k & 7;
        int ct = n >> 4, n2 = n & 15;
        Ws[((((kk * 8 + ct) * 4 + qq) * 16 + n2) << 3) + j] = f2bf(W[idx]);
    } else {
        int* h = (int*)smem;
        for (int i = tid; i < NBUC; i += 512) h[i] = 0;
        __syncthreads();
        int nhb = nb - PWB;
        int chunk = (E + nhb - 1) / nhb;
        int s = (bid - PWB) * chunk, e = min(E, s + chunk);
        for (int i = s + tid; i < e; i += 512)
            atomicAdd(&h[dst[i] >> 7], 1);
        __syncthreads();
        for (int i = tid; i < NBUC; i += 512) {
            int v = h[i];
            if (v) atomicAdd(&tot[i], v);
        }
    }
    g.sync();

    // ---------------- B: scan bucket totals (block 0) ----------------
    if (bid == 0) {
        int* a = (int*)smem;
        int v0 = tot[2 * tid], v1 = tot[2 * tid + 1];
        int sp = v0 + v1;
        a[tid] = sp;
        __syncthreads();
        for (int off = 1; off < 512; off <<= 1) {
            int v = (tid >= off) ? a[tid - off] : 0;
            __syncthreads();
            a[tid] += v;
            __syncthreads();
        }
        int ex = a[tid] - sp;                      // exclusive over pairs
        base[2 * tid] = ex;         gcnt[2 * tid] = ex;
        base[2 * tid + 1] = ex + v0; gcnt[2 * tid + 1] = ex + v0;
        if (tid == 511) base[NBUC] = E;
    }
    g.sync();

    // ---------------- C: reservation scatter || layer-1 GEMM ----------------
    const int SCB = nb >> 1;
    if (bid < SCB) {
        int* cnt = (int*)smem;
        for (int i = tid; i < NBUC; i += 512) cnt[i] = 0;
        __syncthreads();
        int chunk = (E + SCB - 1) / SCB;
        int s = bid * chunk, e = min(E, s + chunk);
        for (int i = s + tid; i < e; i += 512)
            atomicAdd(&cnt[dst[i] >> 7], 1);
        __syncthreads();
        for (int i = tid; i < NBUC; i += 512) {
            int c = cnt[i];
            cnt[i] = c ? atomicAdd(&gcnt[i], c) : 0;   // LDS cursor := global base
        }
        __syncthreads();
        for (int i = s + tid; i < e; i += 512) {
            int d = dst[i];
            int pos = atomicAdd(&cnt[d >> 7], 1);
            part[pos] = src[i] | ((d & 127) << 17);    // src < 2^17, local in [0,128)
        }
    } else {
        // gemm1: 128-row tiles, 8 waves x 16 rows; B-frags straight from the
        // 32KB L1-resident W1s table (no LDS staging).  Y1 unscaled bf16.
        int ntile = (N + 127) >> 7;
        unsigned short* lds = (unsigned short*)smem;   // 64 x 136 epilogue stage
        for (int tile = bid - SCB; tile < ntile; tile += nb - SCB) {
            int row0 = (tile << 7) + wave * 16;
            int arow = row0 + nn;
            int arc = arow < N ? arow : N - 1;
            f32x4 acc[8];
#pragma unroll
            for (int ct = 0; ct < 8; ++ct) acc[ct] = (f32x4){0.f, 0.f, 0.f, 0.f};
#pragma unroll
            for (int kk = 0; kk < 4; ++kk) {
                const float* xp = emb + (size_t)arc * EMB + kk * 32 + q * 8;
                float4 u0 = *(const float4*)xp;
                float4 u1 = *(const float4*)(xp + 4);
                short8 af;
                af[0] = (short)f2bf(u0.x); af[1] = (short)f2bf(u0.y);
                af[2] = (short)f2bf(u0.z); af[3] = (short)f2bf(u0.w);
                af[4] = (short)f2bf(u1.x); af[5] = (short)f2bf(u1.y);
                af[6] = (short)f2bf(u1.z); af[7] = (short)f2bf(u1.w);
#pragma unroll
                for (int ct = 0; ct < 8; ++ct) {
                    short8 bf = *(const short8*)(W1s +
                        ((((kk * 8 + ct) * 4 + q) * 16 + nn) << 3));
                    acc[ct] = __builtin_amdgcn_mfma_f32_16x16x32_bf16(af, bf, acc[ct], 0, 0, 0);
                }
            }
            // epilogue in two 64-row halves through the 17.4KB stage
#pragma unroll
            for (int half = 0; half < 2; ++half) {
                __syncthreads();
                if ((wave >> 2) == half) {
                    int wl = wave & 3;
#pragma unroll
                    for (int ct = 0; ct < 8; ++ct)
#pragma unroll
                        for (int r = 0; r < 4; ++r)
                            lds[(wl * 16 + q * 4 + r) * 136 + ct * 16 + nn] =
                                f2bf(acc[ct][r]);
                }
                __syncthreads();
                int rbase = (tile << 7) + half * 64;
                for (int i = tid; i < 1024; i += 512) {
                    int row = i >> 4, off = i & 15;
                    int grow = rbase + row;
                    if (grow < N)
                        *((uint4*)(Y1 + (size_t)grow * EMB) + off) =
                            *(const uint4*)(lds + row * 136 + off * 8);
                }
            }
            __syncthreads();
        }
    }
    g.sync();

    // ---------------- D: bucket -> CSR ----------------
    {
        int nbuck = (N + 127) >> 7;
        int* hist = (int*)smem;
        int* sc   = hist + 128;
        int* cnt  = sc + 128;
        for (int b = bid; b < nbuck; b += nb) {
            int n0 = b << 7;
            int nn2 = min(128, N - n0);
            int s = base[b], e = base[b + 1];
            if (tid < 128) hist[tid] = 0;
            __syncthreads();
            for (int i = s + tid; i < e; i += 512)
                atomicAdd(&hist[part[i] >> 17], 1);
            __syncthreads();
            if (tid < 128) sc[tid] = hist[tid];
            __syncthreads();
            for (int off = 1; off < 128; off <<= 1) {
                int v = 0;
                if (tid < 128 && tid >= off) v = sc[tid - off];
                __syncthreads();
                if (tid < 128) sc[tid] += v;
                __syncthreads();
            }
            if (tid < 128) {
                int ex = sc[tid] - hist[tid];
                cnt[tid] = ex;
                if (tid < nn2) {
                    R[n0 + tid] = s + ex;
                    dis[n0 + tid] = rsqrtf((float)hist[tid] + 1.0f);   // +1 self-loop
                }
            }
            if (b == 0 && tid == 0) R[N] = E;
            __syncthreads();
            for (int i = s + tid; i < e; i += 512) {
                int p = part[i];
                int pos = atomicAdd(&cnt[p >> 17], 1);
                adj[s + pos] = p & 0x1FFFF;
            }
            __syncthreads();   // cnt reused next bucket
        }
    }
    g.sync();

    // ------- E: fused gather1 (dis-fold) + relu + layer-2 GEMM (dis-scaled) -------
    {
        int ntile = (N + 15) >> 4;                 // 16 nodes per tile
        unsigned short* Hs = (unsigned short*)smem; // [16][136] bf16
        const int nl = tid >> 5;                   // node-local 0..15
        const int lj = (tid & 31) * 4;             // 4 dims per thread
        for (int tile = bid; tile < ntile; tile += nb) {
            int n = (tile << 4) + nl;
            float a0 = 0.f, a1 = 0.f, a2 = 0.f, a3 = 0.f;
            if (n < N) {
                float dv = dis[n];
                uint2 sv = *(const uint2*)(Y1 + (size_t)n * EMB + lj);
                acc_fma4(sv, dv, a0, a1, a2, a3);          // self term
                int e = R[n];
                const int re = R[n + 1];
                for (; e + 3 < re; e += 4) {
                    int s0 = adj[e], s1 = adj[e + 1], s2 = adj[e + 2], s3 = adj[e + 3];
                    float d0 = dis[s0], d1 = dis[s1], d2 = dis[s2], d3 = dis[s3];
                    uint2 v0 = *(const uint2*)(Y1 + (size_t)s0 * EMB + lj);
                    uint2 v1 = *(const uint2*)(Y1 + (size_t)s1 * EMB + lj);
                    uint2 v2 = *(const uint2*)(Y1 + (size_t)s2 * EMB + lj);
                    uint2 v3 = *(const uint2*)(Y1 + (size_t)s3 * EMB + lj);
                    acc_fma4(v0, d0, a0, a1, a2, a3);
                    acc_fma4(v1, d1, a0, a1, a2, a3);
                    acc_fma4(v2, d2, a0, a1, a2, a3);
                    acc_fma4(v3, d3, a0, a1, a2, a3);
                }
                for (; e < re; ++e) {
                    int s0 = adj[e];
                    uint2 v0 = *(const uint2*)(Y1 + (size_t)s0 * EMB + lj);
                    acc_fma4(v0, dis[s0], a0, a1, a2, a3);
                }
                float4 bb = *(const float4*)(b1 + lj);
                a0 = fmaxf(dv * a0 + bb.x, 0.f);
                a1 = fmaxf(dv * a1 + bb.y, 0.f);
                a2 = fmaxf(dv * a2 + bb.z, 0.f);
                a3 = fmaxf(dv * a3 + bb.w, 0.f);
            }
            uint2 pk;
            pk.x = (unsigned)f2bf(a0) | ((unsigned)f2bf(a1) << 16);
            pk.y = (unsigned)f2bf(a2) | ((unsigned)f2bf(a3) << 16);
            *(uint2*)(Hs + nl * 136 + lj) = pk;            // zero rows for n>=N
            __syncthreads();

            // MFMA: 16x128 H @ 128x128 W2; wave = one 16-col tile (ct = wave)
            f32x4 acc = (f32x4){0.f, 0.f, 0.f, 0.f};
#pragma unroll
            for (int kk = 0; kk < 4; ++kk) {
                short8 af = *(const short8*)(Hs + nn * 136 + kk * 32 + q * 8);
                short8 bf = *(const short8*)(W2s +
                    ((((kk * 8 + wave) * 4 + q) * 16 + nn) << 3));
                acc = __builtin_amdgcn_mfma_f32_16x16x32_bf16(af, bf, acc, 0, 0, 0);
            }
            __syncthreads();   // all A-frag reads done before D overwrites Hs

            // D map: row m=q*4+r, col wave*16+nn; scale rows by dis[row]
#pragma unroll
            for (int r = 0; r < 4; ++r) {
                int m = q * 4 + r;
                int gm = (tile << 4) + m;
                float dm = dis[gm < N ? gm : N - 1];
                Hs[m * 136 + wave * 16 + nn] = f2bf(acc[r] * dm);
            }
            __syncthreads();

            // coalesced store: 16 rows x 256B, 8B per thread
            {
                int row = tid >> 5, off = tid & 31;
                int gr = (tile << 4) + row;
                if (gr < N)
                    *((uint2*)(Y2 + (size_t)gr * EMB) + off) =
                        *(const uint2*)(Hs + row * 136 + off * 4);
            }
            __syncthreads();   // store reads done before next tile's pack
        }
    }
    g.sync();

    // ---------------- F: gather2 (plain adds; Y2 pre-scaled) ----------------
    {
        int nch = (N + 15) >> 4;                   // 16 nodes per block-chunk
        const int nl = tid >> 5;
        const int lj = (tid & 31) * 4;
        for (int ch = bid; ch < nch; ch += nb) {
            int n = (ch << 4) + nl;
            if (n >= N) continue;
            float a0 = 0.f, a1 = 0.f, a2 = 0.f, a3 = 0.f;
            uint2 sv = *(const uint2*)(Y2 + (size_t)n * EMB + lj);
            acc_bf4(sv, a0, a1, a2, a3);
            int e = R[n];
            const int re = R[n + 1];
            for (; e + 3 < re; e += 4) {
                int s0 = adj[e], s1 = adj[e + 1], s2 = adj[e + 2], s3 = adj[e + 3];
                uint2 v0 = *(const uint2*)(Y2 + (size_t)s0 * EMB + lj);
                uint2 v1 = *(const uint2*)(Y2 + (size_t)s1 * EMB + lj);
                uint2 v2 = *(const uint2*)(Y2 + (size_t)s2 * EMB + lj);
                uint2 v3 = *(const uint2*)(Y2 + (size_t)s3 * EMB + lj);
                acc_bf4(v0, a0, a1, a2, a3); acc_bf4(v1, a0, a1, a2, a3);
                acc_bf4(v2, a0, a1, a2, a3); acc_bf4(v3, a0, a1, a2, a3);
            }
            for (; e < re; ++e) {
                uint2 v0 = *(const uint2*)(Y2 + (size_t)adj[e] * EMB + lj);
                acc_bf4(v0, a0, a1, a2, a3);
            }
            float dv = dis[n];
            float4 bb = *(const float4*)(b2 + lj);
            float4 o = { dv * a0 + bb.x, dv * a1 + bb.y,
                         dv * a2 + bb.z, dv * a3 + bb.w };
            *(float4*)(out + (size_t)n * EMB + lj) = o;
        }
    }
}

extern "C" void kernel_launch(void* const* d_in, const int* in_sizes, int n_in,
                              void* d_out, int out_size, void* d_ws, size_t ws_size,
                              hipStream_t stream) {
    const int* ei = (const int*)d_in[0];
    int E = in_sizes[0] / 2;
    const float* emb = (const float*)d_in[2];
    int N = in_sizes[2] / EMB;
    const float* W1 = (const float*)d_in[3];
    const float* b1 = (const float*)d_in[4];
    const float* W2 = (const float*)d_in[5];
    const float* b2 = (const float*)d_in[6];
    float* out = (float*)d_out;

    const int* src = ei;
    const int* dstp = ei + E;

    // ws: dis | R | base | tot | gcnt | adj | W1s | W2s | Y2 (part overlays Y2;
    // dead before phase E writes Y2).  Y1 lives in d_out bytes (dead before
    // phase F writes d_out f32).
    char* w = (char*)d_ws;
    auto take = [&](size_t bytes) { char* p = w; w += (bytes + 511) & ~(size_t)511; return p; };
    float* dis  = (float*)take((size_t)N * 4);
    int*   R    = (int*)  take((size_t)(N + 1) * 4);
    int*   base = (int*)  take((size_t)(NBUC + 1) * 4);
    int*   tot  = (int*)  take((size_t)NBUC * 4);
    int*   gcnt = (int*)  take((size_t)NBUC * 4);
    int*   adj  = (int*)  take((size_t)E * 4);
    unsigned short* W1s = (unsigned short*)take((size_t)EMB * EMB * 2);
    unsigned short* W2s = (unsigned short*)take((size_t)EMB * EMB * 2);
    unsigned short* Y2  = (unsigned short*)take((size_t)N * EMB * 2);
    int*   part = (int*)Y2;                                  // overlay (dead before Y2)
    unsigned short* Y1 = (unsigned short*)d_out;             // overlay in d_out

    // Grid sized to guaranteed co-residency (cooperative requirement).
    static int maxb = -1;
    if (maxb < 0) {
        hipOccupancyMaxActiveBlocksPerMultiprocessor(&maxb, (const void*)k_all, 512, 0);
        if (maxb < 1) maxb = 1;
    }
    int nb = maxb * 256;
    if (nb > 1024) nb = 1024;
    if (nb < 128) nb = 128;

    void* args[] = {
        (void*)&src, (void*)&dstp, (void*)&E, (void*)&emb,
        (void*)&W1, (void*)&b1, (void*)&W2, (void*)&b2,
        (void*)&out, (void*)&N,
        (void*)&tot, (void*)&base, (void*)&gcnt,
        (void*)&R, (void*)&adj, (void*)&dis,
        (void*)&W1s, (void*)&W2s, (void*)&part,
        (void*)&Y1, (void*)&Y2
    };
    hipLaunchCooperativeKernel((void*)k_all, dim3(nb), dim3(512), args, 0, stream);
}